// Round 7
// baseline (646.617 us; speedup 1.0000x reference)
//
#include <hip/hip_runtime.h>

#define BB 4
#define TT 2048
#define DD 1024
#define HH 16
#define DHH 64

using half8  = __attribute__((ext_vector_type(8))) _Float16;
using half4v = __attribute__((ext_vector_type(4))) _Float16;
using f32x4  = __attribute__((ext_vector_type(4))) float;

#define EXP2C 0.18033688011112042f  // log2(e)/8

__device__ __forceinline__ float fexp2(float x) {
#if __has_builtin(__builtin_amdgcn_exp2f)
  return __builtin_amdgcn_exp2f(x);
#else
  return exp2f(x);
#endif
}

__device__ __forceinline__ void gload_lds16(const _Float16* g, _Float16* l) {
  __builtin_amdgcn_global_load_lds((const __attribute__((address_space(1))) void*)g,
                                   (__attribute__((address_space(3))) void*)l, 16, 0, 0);
}

// ---------------- fused fp32 -> fp16 convert: x + 4 weights in one launch ----------------
__global__ void cvt_all(const float* __restrict__ x,
                        const float* __restrict__ wq, const float* __restrict__ wk,
                        const float* __restrict__ wv, const float* __restrict__ wo,
                        _Float16* __restrict__ xh,
                        _Float16* __restrict__ wqh, _Float16* __restrict__ wkh,
                        _Float16* __restrict__ wvh, _Float16* __restrict__ woh) {
  const float* s; _Float16* d; int n8, b0, nb;
  int b = blockIdx.x;
  if (b < 512) { s = x; d = xh; n8 = BB * TT * DD / 8; b0 = b; nb = 512; }
  else {
    int wsel = (b - 512) >> 6;
    b0 = (b - 512) & 63; nb = 64; n8 = DD * DD / 8;
    s = wsel == 0 ? wq : wsel == 1 ? wk : wsel == 2 ? wv : wo;
    d = wsel == 0 ? wqh : wsel == 1 ? wkh : wsel == 2 ? wvh : woh;
  }
  for (int i = b0 * 256 + threadIdx.x; i < n8; i += nb * 256) {
    const float4* p = (const float4*)(s + (size_t)i * 8);
    float4 a = p[0], bb = p[1];
    half8 h;
    h[0] = (_Float16)a.x; h[1] = (_Float16)a.y; h[2] = (_Float16)a.z; h[3] = (_Float16)a.w;
    h[4] = (_Float16)bb.x; h[5] = (_Float16)bb.y; h[6] = (_Float16)bb.z; h[7] = (_Float16)bb.w;
    *(half8*)(d + (size_t)i * 8) = h;
  }
}

// common staging macro (identifiers A, Bw, row0, col0, K, tid, As, Bs must exist)
#define GEMM_STAGE(K0, BSEL)                                                        \
  _Pragma("unroll") for (int it = 0; it < 4; ++it) {                                \
    int chunk = tid + it * 256;                                                     \
    int r = chunk >> 3, pb = chunk & 7, lb = pb ^ (r & 7);                          \
    gload_lds16(A + (size_t)(row0 + r) * K + (K0) * 64 + lb * 8, As[BSEL] + chunk * 8);  \
    gload_lds16(Bw + (size_t)(col0 + r) * K + (K0) * 64 + lb * 8, Bs[BSEL] + chunk * 8); \
  }

// ---------------- fused QKV NT GEMM: one launch, blockIdx.y selects weight ----------------
__global__ __launch_bounds__(256, 2) void gemm_qkv(const _Float16* __restrict__ A,
                                                   const _Float16* __restrict__ Wqh,
                                                   const _Float16* __restrict__ Wkh,
                                                   const _Float16* __restrict__ Wvh,
                                                   const float* __restrict__ bq,
                                                   const float* __restrict__ bk,
                                                   const float* __restrict__ bv,
                                                   _Float16* __restrict__ qh,
                                                   _Float16* __restrict__ kh,
                                                   _Float16* __restrict__ vTh) {
  constexpr int K = 1024;
  __shared__ _Float16 As[2][128 * 64];
  __shared__ _Float16 Bs[2][128 * 64];
  const int tid = threadIdx.x;
  const int l = tid & 63, w = tid >> 6;
  const int wm = w >> 1, wn = w & 1;
  const int lg = l >> 4, lr16 = l & 15;
  const int wsel = (int)blockIdx.y >> 3;
  const _Float16* Bw = wsel == 0 ? Wqh : wsel == 1 ? Wkh : Wvh;
  const float* bias = wsel == 0 ? bq : wsel == 1 ? bk : bv;
  const int row0 = blockIdx.x * 128, col0 = ((int)blockIdx.y & 7) * 128;

  f32x4 acc[4][4];
#pragma unroll
  for (int i = 0; i < 4; ++i)
#pragma unroll
    for (int j = 0; j < 4; ++j) acc[i][j] = (f32x4)0.0f;

  GEMM_STAGE(0, 0);
  int cur = 0;
  for (int k0 = 0; k0 < 16; ++k0) {
    __syncthreads();
    if (k0 < 15) GEMM_STAGE(k0 + 1, cur ^ 1);
#pragma unroll
    for (int kb = 0; kb < 2; ++kb) {
      half8 a[4], b[4];
#pragma unroll
      for (int f = 0; f < 4; ++f) {
        int ar = wm * 64 + f * 16 + lr16;
        a[f] = *(const half8*)(As[cur] + ar * 64 + ((kb * 4 + lg) ^ (ar & 7)) * 8);
        int br = wn * 64 + f * 16 + lr16;
        b[f] = *(const half8*)(Bs[cur] + br * 64 + ((kb * 4 + lg) ^ (br & 7)) * 8);
      }
#pragma unroll
      for (int i = 0; i < 4; ++i)
#pragma unroll
        for (int j = 0; j < 4; ++j)
          acc[i][j] = __builtin_amdgcn_mfma_f32_16x16x32_f16(a[i], b[j], acc[i][j], 0, 0, 0);
    }
    cur ^= 1;
  }

  // epilogue: C/D layout col=lane&15, row=(lane>>4)*4+reg  [m89-verified]
#pragma unroll
  for (int fi = 0; fi < 4; ++fi) {
#pragma unroll
    for (int fj = 0; fj < 4; ++fj) {
      int gi0 = row0 + wm * 64 + fi * 16 + lg * 4;
      int gj = col0 + wn * 64 + fj * 16 + lr16;
      float bj = bias[gj];
      int b = gi0 >> 11, t0 = gi0 & 2047;
      int h = gj >> 6, dh = gj & 63;
      if (wsel < 2) {
        _Float16* O = wsel ? kh : qh;
#pragma unroll
        for (int r = 0; r < 4; ++r)
          O[(((size_t)(b * HH + h) * TT + (t0 + r)) << 6) + dh] = (_Float16)(acc[fi][fj][r] + bj);
      } else {
        half4v tmp;
#pragma unroll
        for (int r = 0; r < 4; ++r) tmp[r] = (_Float16)(acc[fi][fj][r] + bj);
        *(half4v*)(vTh + (((size_t)(b * HH + h) * DHH + dh) * TT + t0)) = tmp;
      }
    }
  }
}

// ---------------- final NT GEMM: out[M=8192,N=1024] = zh @ Wo^T + bo (fp32) ----------------
__global__ __launch_bounds__(256, 2) void gemm_out(const _Float16* __restrict__ A,
                                                   const _Float16* __restrict__ Bw,
                                                   const float* __restrict__ bias,
                                                   float* __restrict__ Cout) {
  constexpr int K = 1024;
  __shared__ _Float16 As[2][128 * 64];
  __shared__ _Float16 Bs[2][128 * 64];
  const int tid = threadIdx.x;
  const int l = tid & 63, w = tid >> 6;
  const int wm = w >> 1, wn = w & 1;
  const int lg = l >> 4, lr16 = l & 15;
  const int row0 = blockIdx.x * 128, col0 = blockIdx.y * 128;

  f32x4 acc[4][4];
#pragma unroll
  for (int i = 0; i < 4; ++i)
#pragma unroll
    for (int j = 0; j < 4; ++j) acc[i][j] = (f32x4)0.0f;

  GEMM_STAGE(0, 0);
  int cur = 0;
  for (int k0 = 0; k0 < 16; ++k0) {
    __syncthreads();
    if (k0 < 15) GEMM_STAGE(k0 + 1, cur ^ 1);
#pragma unroll
    for (int kb = 0; kb < 2; ++kb) {
      half8 a[4], b[4];
#pragma unroll
      for (int f = 0; f < 4; ++f) {
        int ar = wm * 64 + f * 16 + lr16;
        a[f] = *(const half8*)(As[cur] + ar * 64 + ((kb * 4 + lg) ^ (ar & 7)) * 8);
        int br = wn * 64 + f * 16 + lr16;
        b[f] = *(const half8*)(Bs[cur] + br * 64 + ((kb * 4 + lg) ^ (br & 7)) * 8);
      }
#pragma unroll
      for (int i = 0; i < 4; ++i)
#pragma unroll
        for (int j = 0; j < 4; ++j)
          acc[i][j] = __builtin_amdgcn_mfma_f32_16x16x32_f16(a[i], b[j], acc[i][j], 0, 0, 0);
    }
    cur ^= 1;
  }

#pragma unroll
  for (int fi = 0; fi < 4; ++fi) {
#pragma unroll
    for (int fj = 0; fj < 4; ++fj) {
      int gi0 = row0 + wm * 64 + fi * 16 + lg * 4;
      int gj = col0 + wn * 64 + fj * 16 + lr16;
      float bj = bias[gj];
#pragma unroll
      for (int r = 0; r < 4; ++r)
        Cout[(size_t)(gi0 + r) * DD + gj] = acc[fi][fj][r] + bj;
    }
  }
}

// ---------------- fused attention: single-pass, fp16 S-buffer, LINEAR A-write -------------
// Block = 32 q-rows, 8 waves = 2 row-groups (wr) x 4 s-slices (ws). Dynamic LDS 160KB:
//   S-buf [32][2048] fp16 (128KB, granule^q swizzle)  K [2][64][64] (16KB)  V^T [2][64][64] (16KB)
// Per 64-col tile, wave (wr,ws): QK^T (S^T: mfma32(K,Q)) for its 16-col slice -> lane holds
// 4 exp values of ONE q-row; rowsum in reg; fp16 -> S-buf; PV DIRECT from registers:
// the S^T C-frag (q=l&15, s=lg*4+r) IS the A-frag of mfma_f32_16x16x16f16 -> z += P x V.
// After the loop: rowsum reduce, then EPILOGUE streams S-buf*inv to A as ONE fully linear
// 256KB contiguous write per block (the fill-kernel pattern that measures 6.5 TB/s).
__global__ __launch_bounds__(512, 1) void attn_kernel(const _Float16* __restrict__ qh,
                                                      const _Float16* __restrict__ kh,
                                                      const _Float16* __restrict__ vTh,
                                                      const float* __restrict__ gates,
                                                      float* __restrict__ Aout,
                                                      _Float16* __restrict__ zh) {
  extern __shared__ char sm[];
  _Float16* Sb = (_Float16*)sm;                       // 131072 B
  _Float16* Ksm = (_Float16*)(sm + 131072);           // 2 x 8192 B
  _Float16* Vsm = (_Float16*)(sm + 147456);           // 2 x 8192 B
  float* rsscr  = (float*)(sm + 131072);              // reused after loop (K region)
  float* invscr = (float*)(sm + 131072 + 512);
  float* zscr   = (float*)sm;                         // reused after A-epilogue (S region)

  const int tid = threadIdx.x;
  const int l = tid & 63, w = tid >> 6;
  const int lg = l >> 4, lr16 = l & 15;
  const int wr = w >> 2, ws = w & 3;
  const int blk = ((int)blockIdx.x & 7) * 512 + ((int)blockIdx.x >> 3);  // XCD chunk swizzle
  const int rt = blk & 63, bh = blk >> 6;
  const _Float16* Qp = qh + (size_t)bh * TT * DHH + (size_t)rt * 32 * DHH;
  const _Float16* Kp = kh + (size_t)bh * TT * DHH;
  const _Float16* Vp = vTh + (size_t)bh * DHH * TT;
  const float gate = gates[bh];

  // ---- stage Q [32][64] into K-buffer scratch, lift to registers ----
  if (tid < 256) {
    int r = tid >> 3, pb = tid & 7, lb = pb ^ (r & 7);
    gload_lds16(Qp + (size_t)r * DHH + lb * 8, Ksm + tid * 8);
  }
  asm volatile("s_waitcnt vmcnt(0)" ::: "memory");
  __syncthreads();
  const int q32 = wr * 16 + lr16;  // this lane's q-row (local)
  const half8 aQ0 = *(const half8*)(Ksm + q32 * 64 + ((lg ^ (q32 & 7)) * 8));
  const half8 aQ1 = *(const half8*)(Ksm + q32 * 64 + (((4 + lg) ^ (q32 & 7)) * 8));
  __syncthreads();  // everyone done with Q scratch before K staging overwrites it

#define STAGE_K(CT, BSEL) {                                                       \
    int r = tid >> 3, pb = tid & 7, lb = pb ^ (r & 7);                            \
    gload_lds16(Kp + (size_t)((CT) * 64 + r) * DHH + lb * 8,                      \
                Ksm + (BSEL) * 4096 + tid * 8); }
#define STAGE_V(CT, BSEL) {                                                       \
    int r = tid >> 3, pb = tid & 7, lb = pb ^ (r & 7);                            \
    gload_lds16(Vp + (size_t)r * TT + (CT) * 64 + lb * 8,                         \
                Vsm + (BSEL) * 4096 + tid * 8); }

  // -------- single pass over 32 K/V tiles --------
  STAGE_K(0, 0);
  STAGE_V(0, 0);
  asm volatile("s_waitcnt vmcnt(0)\n\ts_barrier" ::: "memory");
  float rs = 0.f;
  f32x4 z[4];
#pragma unroll
  for (int j = 0; j < 4; ++j) z[j] = (f32x4)0.0f;
  const int kr = ws * 16 + lr16;
  int cur = 0;
  for (int ct = 0; ct < 32; ++ct) {
    if (ct < 31) {
      STAGE_K(ct + 1, cur ^ 1);
      STAGE_V(ct + 1, cur ^ 1);
    }
    __builtin_amdgcn_sched_barrier(0);
    const _Float16* Kc = Ksm + cur * 4096;
    const _Float16* Vc = Vsm + cur * 4096;
    // QK^T for this wave's 16-col slice (S^T: lane -> q=lr16-row, s=ws*16+lg*4+r)
    f32x4 s = (f32x4)0.0f;
    half8 bK0 = *(const half8*)(Kc + kr * 64 + ((lg ^ (kr & 7)) * 8));
    half8 bK1 = *(const half8*)(Kc + kr * 64 + (((4 + lg) ^ (kr & 7)) * 8));
    __builtin_amdgcn_s_setprio(1);
    s = __builtin_amdgcn_mfma_f32_16x16x32_f16(bK0, aQ0, s, 0, 0, 0);
    s = __builtin_amdgcn_mfma_f32_16x16x32_f16(bK1, aQ1, s, 0, 0, 0);
    __builtin_amdgcn_s_setprio(0);
    // exp -> rowsum partial + fp16 pack
    half4v ph;
#pragma unroll
    for (int j = 0; j < 4; ++j) {
      float p = fexp2(s[j] * EXP2C);
      rs += p;
      ph[j] = (_Float16)p;
    }
    // S-buf write: row q32, cols ct*64 + ws*16 + lg*4 .. +4 (granule-xor swizzled)
    {
      int g8 = ct * 8 + ws * 2 + (lg >> 1);
      *(half4v*)(Sb + q32 * 2048 + ((g8 ^ (q32 & 15)) * 8) + (lg & 1) * 4) = ph;
    }
    // PV direct: z[q][dh] += P[q][s] * V[s][dh] via 16x16x16 (A = ph, reg-fed)
    __builtin_amdgcn_s_setprio(1);
#pragma unroll
    for (int fc2 = 0; fc2 < 4; ++fc2) {
      int vr = fc2 * 16 + lr16;
      half4v bV = *(const half4v*)(Vc + vr * 64 + (((ws * 2 + (lg >> 1)) ^ (vr & 7)) * 8) +
                                   (lg & 1) * 4);
      z[fc2] = __builtin_amdgcn_mfma_f32_16x16x16f16(ph, bV, z[fc2], 0, 0, 0);
    }
    __builtin_amdgcn_s_setprio(0);
    asm volatile("s_waitcnt vmcnt(0) lgkmcnt(0)\n\ts_barrier" ::: "memory");
    cur ^= 1;
  }

  // -------- rowsum reduce: lanes sharing q (lg), then the 4 ws waves --------
  rs += __shfl_xor(rs, 16, 64);
  rs += __shfl_xor(rs, 32, 64);
  if (lg == 0) rsscr[(wr * 4 + ws) * 16 + lr16] = rs;
  __syncthreads();
  {
    float rtot = rsscr[(wr * 4 + 0) * 16 + lr16] + rsscr[(wr * 4 + 1) * 16 + lr16] +
                 rsscr[(wr * 4 + 2) * 16 + lr16] + rsscr[(wr * 4 + 3) * 16 + lr16];
    if (ws == 0 && lg == 0) invscr[wr * 16 + lr16] = gate / rtot;
  }
  __syncthreads();

  // -------- A epilogue: fully LINEAR 256KB contiguous write per block --------
  {
    float* Ab = Aout + (size_t)bh * TT * TT + (size_t)rt * 32 * TT;
    for (int it = 0; it < 16; ++it) {
      int flat = it * 4096 + tid * 8;
      int q = flat >> 11, col = flat & 2047, g8 = col >> 3;
      half8 v = *(const half8*)(Sb + q * 2048 + ((g8 ^ (q & 15)) * 8));
      float iv = invscr[q];
      f32x4 o0, o1;
#pragma unroll
      for (int k = 0; k < 4; ++k) { o0[k] = (float)v[k] * iv; o1[k] = (float)v[k + 4] * iv; }
      *(f32x4*)(Ab + flat) = o0;
      *(f32x4*)(Ab + flat + 4) = o1;
    }
  }
  __syncthreads();  // S-buf reads done; reuse region for z reduce

  // -------- z cross-ws reduce (4 partials per row) + write zh --------
  // z frag layout: row q = wr*16 + lg*4 + reg, col dh = fc2*16 + lr16
#pragma unroll
  for (int fc2 = 0; fc2 < 4; ++fc2)
#pragma unroll
    for (int j = 0; j < 4; ++j)
      zscr[((size_t)ws * 32 + wr * 16 + lg * 4 + j) * 64 + fc2 * 16 + lr16] = z[fc2][j];
  __syncthreads();
  {
    int q = tid >> 4, dh0 = (tid & 15) * 4;
    f32x4 acc = (f32x4)0.0f;
#pragma unroll
    for (int s4 = 0; s4 < 4; ++s4) acc += *(const f32x4*)(zscr + ((size_t)s4 * 32 + q) * 64 + dh0);
    float iv = invscr[q];
    half4v hz;
#pragma unroll
    for (int k = 0; k < 4; ++k) hz[k] = (_Float16)(acc[k] * iv);
    const int b = bh >> 4, h = bh & 15;
    *(half4v*)(zh + ((size_t)(b * TT + rt * 32 + q)) * DD + h * 64 + dh0) = hz;
  }
}

extern "C" void kernel_launch(void* const* d_in, const int* in_sizes, int n_in,
                              void* d_out, int out_size, void* d_ws, size_t ws_size,
                              hipStream_t stream) {
  const float* x     = (const float*)d_in[0];
  const float* gates = (const float*)d_in[1];
  const float* Wq    = (const float*)d_in[2];
  const float* bq    = (const float*)d_in[3];
  const float* Wk    = (const float*)d_in[4];
  const float* bk    = (const float*)d_in[5];
  const float* Wv    = (const float*)d_in[6];
  const float* bv    = (const float*)d_in[7];
  const float* Wo    = (const float*)d_in[8];
  const float* bo    = (const float*)d_in[9];

  float* out  = (float*)d_out;
  float* Aout = out + (size_t)BB * TT * DD;

  char* ws = (char*)d_ws;
  _Float16* xh  = (_Float16*)(ws);                       // 16 MB (reused as zh)
  _Float16* Wqh = (_Float16*)(ws + (16ull << 20));       // 2 MB
  _Float16* Wkh = (_Float16*)(ws + (18ull << 20));       // 2 MB
  _Float16* Wvh = (_Float16*)(ws + (20ull << 20));       // 2 MB
  _Float16* Woh = (_Float16*)(ws + (22ull << 20));       // 2 MB
  _Float16* qh  = (_Float16*)(ws + (24ull << 20));       // 16 MB
  _Float16* kh  = (_Float16*)(ws + (40ull << 20));       // 16 MB
  _Float16* vTh = (_Float16*)(ws + (56ull << 20));       // 16 MB
  _Float16* zh  = xh;  // x no longer needed once V-proj done

  static bool smem_set = false;
  if (!smem_set) {
    (void)hipFuncSetAttribute((const void*)attn_kernel,
                              hipFuncAttributeMaxDynamicSharedMemorySize, 163840);
    smem_set = true;
  }

  cvt_all<<<768, 256, 0, stream>>>(x, Wq, Wk, Wv, Wo, xh, Wqh, Wkh, Wvh, Woh);

  gemm_qkv<<<dim3(BB * TT / 128, 24), 256, 0, stream>>>(xh, Wqh, Wkh, Wvh, bq, bk, bv,
                                                        qh, kh, vTh);

  attn_kernel<<<BB * HH * (TT / 32), 512, 163840, stream>>>(qh, kh, vTh, gates, Aout, zh);

  gemm_out<<<dim3(BB * TT / 128, DD / 128), 256, 0, stream>>>(zh, Woh, bo, out);
}